// Round 18
// baseline (312.613 us; speedup 1.0000x reference)
//
#include <hip/hip_runtime.h>
#include <stdint.h>

typedef __bf16 bf16x8 __attribute__((ext_vector_type(8)));
typedef float f32x4 __attribute__((ext_vector_type(4)));
typedef unsigned short ushort8v __attribute__((ext_vector_type(8)));

__device__ __forceinline__ void gload_lds16(const void* g, void* l) {
  __builtin_amdgcn_global_load_lds(
      (const __attribute__((address_space(1))) void*)g,
      (__attribute__((address_space(3))) void*)l, 16, 0, 0);
}

__device__ __forceinline__ unsigned short f2bf(float f) {
  union { float f; unsigned int u; } x; x.f = f;
  unsigned int r = x.u + 0x7FFFu + ((x.u >> 16) & 1u);
  return (unsigned short)(r >> 16);
}

__device__ __forceinline__ float bf2f(unsigned short h) {
  union { unsigned int u; float f; } x; x.u = ((unsigned int)h) << 16;
  return x.f;
}

__device__ __forceinline__ float ftanh(float x) {
  float ax = fabsf(x);
  float e = __expf(-2.0f * ax);
  float r = (1.0f - e) / (1.0f + e);
  return copysignf(r, x);
}

// native bf16 casts: compiler emits v_cvt_pk_bf16_f32 (1 op / 2 elems)
__device__ __forceinline__ bf16x8 cvt8(float4 a, float4 b) {
  bf16x8 o;
  o[0] = (__bf16)a.x; o[1] = (__bf16)a.y; o[2] = (__bf16)a.z; o[3] = (__bf16)a.w;
  o[4] = (__bf16)b.x; o[5] = (__bf16)b.y; o[6] = (__bf16)b.z; o[7] = (__bf16)b.w;
  return o;
}

// -------- W1 f32 -> bf16, 16 KB chunks, slot-swizzled (R13-proven) ------
__global__ __launch_bounds__(256) void w1cvt_kernel(
    const float* __restrict__ W1, unsigned short* __restrict__ w1b) {
  const int g = blockIdx.x * 256 + threadIdx.x;
  const int chunk = g >> 10;
  const int d16 = g & 1023;
  const int col = d16 >> 2, s = d16 & 3;
  const int np = chunk >> 5, ks = chunk & 31;
  const float* src = W1 + (size_t)(np * 256 + col) * 1024 + ks * 32 +
                     ((s ^ ((col >> 1) & 3)) * 8);
  const float4 v0 = *(const float4*)src;
  const float4 v1 = *(const float4*)(src + 4);
  ushort8v o;
  o[0] = f2bf(v0.x); o[1] = f2bf(v0.y); o[2] = f2bf(v0.z); o[3] = f2bf(v0.w);
  o[4] = f2bf(v1.x); o[5] = f2bf(v1.y); o[6] = f2bf(v1.z); o[7] = f2bf(v1.w);
  *((ushort8v*)w1b + g) = o;
}

// ---------------- u[b][a] = sum_d dec[b][d] * W2[a][d] ----------------
__global__ __launch_bounds__(256) void dec_proj_kernel(
    const float* __restrict__ dec, const float* __restrict__ W2,
    float* __restrict__ u) {
  __shared__ __align__(16) float w2s[1024];
  const int a = blockIdx.x;
  const int t = threadIdx.x;
  *(float4*)(w2s + t * 4) = *(const float4*)(W2 + (size_t)a * 1024 + t * 4);
  __syncthreads();
  const int wid = t >> 6, l = t & 63;
  for (int bi = 0; bi < 8; ++bi) {
    const int b = wid * 8 + bi;
    const float* dp = dec + (size_t)b * 1024;
    float acc = 0.f;
#pragma unroll
    for (int i = 0; i < 4; ++i) {
      const int k = i * 256 + l * 4;
      const float4 dv = *(const float4*)(dp + k);
      const float4 wv = *(const float4*)(w2s + k);
      acc = fmaf(dv.x, wv.x, acc); acc = fmaf(dv.y, wv.y, acc);
      acc = fmaf(dv.z, wv.z, acc); acc = fmaf(dv.w, wv.w, acc);
    }
#pragma unroll
    for (int m = 1; m < 64; m <<= 1) acc += __shfl_xor(acc, m, 64);
    if (l == 0) u[(size_t)b * 1024 + a] = acc;
  }
}

// ------- fused partial scores (R13 shape) + enc16 piggyback ------------
// 256 thr (2x2 waves), BM=128 BN=256 BK=32, acc[4][8] = 32 indep MFMA.
// A: native-cast staged, TWO pieces per thread (rows 0-63 and 64-127);
// B: gload_lds from pre-swizzled w1b. np==0 blocks store both converted
// A pieces to enc16 (register-held one iteration; store drains over a
// full slot). LDS 49 KB -> 2 blocks/CU.
__global__ __launch_bounds__(256, 2) void scores_kernel(
    const float* __restrict__ enc, const unsigned short* __restrict__ w1b,
    const float* __restrict__ u, const float* __restrict__ vvec,
    float* __restrict__ spart, unsigned short* __restrict__ enc16,
    const int wr16) {
  __shared__ __align__(16) char Al[16384];
  __shared__ __align__(16) char Bl[32768];
  __shared__ __align__(16) float sred[256];

  const int t = threadIdx.x;
  const int bid = blockIdx.x;
  const int np = (bid >> 3) & 3;
  const int panel = (bid & 7) | ((bid >> 5) << 3);
  const int m0 = panel * 128;
  const int n0 = np * 256;
  const int b = panel >> 4;
  const int l = t & 63, wid = t >> 6;
  const int wr = wid >> 1, wc = wid & 1;
  const int lm = l & 15, lg = l >> 4;

  const int soff = (lg ^ ((lm >> 1) & 3)) * 16;
  const int abase = (wr * 64 + lm) * 64 + soff;
  const int bbase = (wc * 128 + lm) * 64 + soff;
  const char* w1base = (const char*)w1b + (size_t)(np * 32) * 16384;
  const float* ub = u + (size_t)b * 1024;

  // A staging: thread t handles row0 = t>>2 and row0+64, k-slot s0 = t&3
  const int row0 = t >> 2;
  const int s0 = t & 3;
  const int xo = (s0 ^ ((row0 >> 1) & 3)) * 8;
  const float* srcA = enc + (size_t)(m0 + row0) * 1024 + xo;
  unsigned short* e16b = enc16 + (size_t)(m0 + row0) * 1024 + xo;
  const int adst = t * 16;
  const bool wr0 = (wr16 != 0) && (np == 0);

  f32x4 acc[4][8];
#pragma unroll
  for (int mi = 0; mi < 4; ++mi)
#pragma unroll
    for (int ni = 0; ni < 8; ++ni) acc[mi][ni] = (f32x4){0.f, 0.f, 0.f, 0.f};

  bf16x8 opend0, opend1; /* converted tile kt, stored at top of iter kt */

  // ---------- prologue: stage K-step 0 into buf 0 (both halves) ----------
#pragma unroll
  for (int i = 0; i < 4; ++i)
    gload_lds16(w1base + i * 4096 + t * 16, Bl + i * 4096 + t * 16);
  {
    const float4 p0 = *(const float4*)srcA;
    const float4 p1 = *(const float4*)(srcA + 4);
    const float4 p2 = *(const float4*)(srcA + 65536);
    const float4 p3 = *(const float4*)(srcA + 65540);
    opend0 = cvt8(p0, p1);
    opend1 = cvt8(p2, p3);
    *(bf16x8*)(Al + adst) = opend0;
    *(bf16x8*)(Al + 4096 + adst) = opend1;
  }
  __syncthreads();

#pragma unroll 2
  for (int kt = 0; kt < 32; ++kt) {
    const int abuf = (kt & 1) * 8192;
    const int bbuf = (kt & 1) * 16384;
    // enc16 writeback of tile kt (ack hides across this whole iteration)
    if (wr0) {
      *(bf16x8*)(e16b + kt * 32) = opend0;
      *(bf16x8*)(e16b + 65536 + kt * 32) = opend1;
    }
    float4 p0, p1, p2, p3;
    if (kt < 31) {
      const char* wn = w1base + (size_t)(kt + 1) * 16384;
#pragma unroll
      for (int i = 0; i < 4; ++i)
        gload_lds16(wn + i * 4096 + t * 16,
                    Bl + (bbuf ^ 16384) + i * 4096 + t * 16);
      const float* sa = srcA + (kt + 1) * 32;
      p0 = *(const float4*)sa;
      p1 = *(const float4*)(sa + 4);
      p2 = *(const float4*)(sa + 65536);
      p3 = *(const float4*)(sa + 65540);
    }
    bf16x8 af[4], bf[8];
#pragma unroll
    for (int mi = 0; mi < 4; ++mi)
      af[mi] = *(const bf16x8*)(Al + abuf + abase + mi * 1024);
#pragma unroll
    for (int ni = 0; ni < 8; ++ni)
      bf[ni] = *(const bf16x8*)(Bl + bbuf + bbase + ni * 1024);
    __builtin_amdgcn_s_setprio(1);
#pragma unroll
    for (int mi = 0; mi < 4; ++mi)
#pragma unroll
      for (int ni = 0; ni < 8; ++ni)
        acc[mi][ni] = __builtin_amdgcn_mfma_f32_16x16x32_bf16(
            af[mi], bf[ni], acc[mi][ni], 0, 0, 0);
    __builtin_amdgcn_s_setprio(0);
    if (kt < 31) {
      opend0 = cvt8(p0, p1);
      opend1 = cvt8(p2, p3);
      *(bf16x8*)(Al + (abuf ^ 8192) + adst) = opend0;
      *(bf16x8*)(Al + (abuf ^ 8192) + 4096 + adst) = opend1;
    }
    __syncthreads(); /* drains gloads + ds_writes + enc16 stores */
  }

  // epilogue: tanh + v-weighted column reduction (R13-proven)
  float rowp[4][4];
#pragma unroll
  for (int mi = 0; mi < 4; ++mi)
#pragma unroll
    for (int j = 0; j < 4; ++j) rowp[mi][j] = 0.f;
#pragma unroll
  for (int ni = 0; ni < 8; ++ni) {
    const int colA = n0 + wc * 128 + ni * 16 + lm;
    const float uu = ub[colA], vv = vvec[colA];
#pragma unroll
    for (int mi = 0; mi < 4; ++mi)
#pragma unroll
      for (int j = 0; j < 4; ++j)
        rowp[mi][j] += ftanh(acc[mi][ni][j] + uu) * vv;
  }
#pragma unroll
  for (int m = 1; m < 16; m <<= 1)
#pragma unroll
    for (int mi = 0; mi < 4; ++mi)
#pragma unroll
      for (int j = 0; j < 4; ++j) rowp[mi][j] += __shfl_xor(rowp[mi][j], m, 64);
  if (lm == 0) {
#pragma unroll
    for (int mi = 0; mi < 4; ++mi)
#pragma unroll
      for (int j = 0; j < 4; ++j)
        sred[wc * 128 + wr * 64 + mi * 16 + lg * 4 + j] = rowp[mi][j];
  }
  __syncthreads();
  if (t < 128) {
    spart[(size_t)np * 65536 + m0 + t] = sred[t] + sred[128 + t];
  }
}

// -------- masked softmax over L: sums 4 partials, writes attn ----------
__global__ __launch_bounds__(256) void softmax_kernel(
    const float* __restrict__ spart, float* __restrict__ out,
    const int* __restrict__ mask) {
  __shared__ float wred[4];
  const int bidx = blockIdx.x;
  const int t = threadIdx.x;
  const int r8 = bidx * 2048 + t * 8;
  float* at = out + 32768 + (size_t)bidx * 2048;
  const int* mk = mask + (size_t)bidx * 2048;
  float v[8] = {0.f, 0.f, 0.f, 0.f, 0.f, 0.f, 0.f, 0.f};
#pragma unroll
  for (int np = 0; np < 4; ++np) {
    const float4 s0 = *(const float4*)(spart + (size_t)np * 65536 + r8);
    const float4 s1 = *(const float4*)(spart + (size_t)np * 65536 + r8 + 4);
    v[0] += s0.x; v[1] += s0.y; v[2] += s0.z; v[3] += s0.w;
    v[4] += s1.x; v[5] += s1.y; v[6] += s1.z; v[7] += s1.w;
  }
  const int4 q0 = *(const int4*)(mk + t * 8);
  const int4 q1 = *(const int4*)(mk + t * 8 + 4);
  int q[8] = {q0.x, q0.y, q0.z, q0.w, q1.x, q1.y, q1.z, q1.w};
  float mx = -3.0e38f;
#pragma unroll
  for (int j = 0; j < 8; ++j) if (q[j] != 0) mx = fmaxf(mx, v[j]);
#pragma unroll
  for (int m = 1; m < 64; m <<= 1) mx = fmaxf(mx, __shfl_xor(mx, m, 64));
  if ((t & 63) == 0) wred[t >> 6] = mx;
  __syncthreads();
  mx = fmaxf(fmaxf(wred[0], wred[1]), fmaxf(wred[2], wred[3]));
  __syncthreads();
  float pp[8]; float sum = 0.f;
#pragma unroll
  for (int j = 0; j < 8; ++j) {
    pp[j] = (q[j] != 0) ? __expf(v[j] - mx) : 0.f;
    sum += pp[j];
  }
#pragma unroll
  for (int m = 1; m < 64; m <<= 1) sum += __shfl_xor(sum, m, 64);
  if ((t & 63) == 0) wred[t >> 6] = sum;
  __syncthreads();
  sum = (wred[0] + wred[1]) + (wred[2] + wred[3]);
  const float inv = 1.0f / sum;
  const float4 o0 = {pp[0] * inv, pp[1] * inv, pp[2] * inv, pp[3] * inv};
  const float4 o1 = {pp[4] * inv, pp[5] * inv, pp[6] * inv, pp[7] * inv};
  *(float4*)(at + t * 8) = o0;
  *(float4*)(at + t * 8 + 4) = o1;
}

// -------- context from bf16 enc copy (R14-verified) --------------------
__global__ __launch_bounds__(256) void context16_kernel(
    const unsigned short* __restrict__ enc16, float* __restrict__ out) {
  __shared__ __align__(16) float attnS[2048];
  __shared__ __align__(16) float red[16 * 132];
  const int bid = blockIdx.x;
  const int b = bid >> 3, ec = bid & 7;
  const int e0 = ec * 128;
  const int t = threadIdx.x;
  const float* attn = out + 32768 + (size_t)b * 2048;
#pragma unroll
  for (int i = 0; i < 8; ++i) attnS[i * 256 + t] = attn[i * 256 + t];
  __syncthreads();
  const int el = (t & 15) * 8;
  const int ls = t >> 4;
  float acc[8];
#pragma unroll
  for (int j = 0; j < 8; ++j) acc[j] = 0.f;
  const unsigned short* eb = enc16 + (size_t)b * 2048 * 1024 + e0 + el;
  for (int l2 = ls; l2 < 2048; l2 += 16) {
    const float a = attnS[l2];
    const ushort8v ev = *(const ushort8v*)(eb + (size_t)l2 * 1024);
#pragma unroll
    for (int j = 0; j < 8; ++j) acc[j] = fmaf(a, bf2f(ev[j]), acc[j]);
  }
#pragma unroll
  for (int j = 0; j < 8; ++j) red[ls * 132 + el + j] = acc[j];
  __syncthreads();
  if (t < 128) {
    float s = 0.f;
#pragma unroll
    for (int i = 0; i < 16; ++i) s += red[i * 132 + t];
    out[(size_t)b * 1024 + e0 + t] = s;
  }
}

// -------- context f32 fallback (R13-proven) ----------------------------
__global__ __launch_bounds__(256) void context_kernel(
    const float* __restrict__ enc, float* __restrict__ out) {
  __shared__ __align__(16) float attnS[2048];
  __shared__ __align__(16) float red[8 * 128];
  const int bid = blockIdx.x;
  const int b = bid >> 3, ec = bid & 7;
  const int e0 = ec * 128;
  const int t = threadIdx.x;
  const float* attn = out + 32768 + (size_t)b * 2048;
#pragma unroll
  for (int i = 0; i < 8; ++i) attnS[i * 256 + t] = attn[i * 256 + t];
  __syncthreads();
  const int el = (t & 31) * 4;
  const int ls = t >> 5;
  f32x4 acc = {0.f, 0.f, 0.f, 0.f};
  const float* ebase = enc + (size_t)b * 2048 * 1024 + e0 + el;
  for (int l2 = ls; l2 < 2048; l2 += 8) {
    const float a = attnS[l2];
    const float4 ev = *(const float4*)(ebase + (size_t)l2 * 1024);
    acc[0] = fmaf(a, ev.x, acc[0]);
    acc[1] = fmaf(a, ev.y, acc[1]);
    acc[2] = fmaf(a, ev.z, acc[2]);
    acc[3] = fmaf(a, ev.w, acc[3]);
  }
  *(f32x4*)(red + ls * 128 + el) = acc;
  __syncthreads();
  if (t < 128) {
    float s = 0.f;
#pragma unroll
    for (int i = 0; i < 8; ++i) s += red[i * 128 + t];
    out[(size_t)b * 1024 + e0 + t] = s;
  }
}

extern "C" void kernel_launch(void* const* d_in, const int* in_sizes, int n_in,
                              void* d_out, int out_size, void* d_ws,
                              size_t ws_size, hipStream_t stream) {
  const float* enc = (const float*)d_in[0];
  const float* dec = (const float*)d_in[1];
  const int* mask = (const int*)d_in[2];
  const float* W1 = (const float*)d_in[3];
  const float* W2 = (const float*)d_in[4];
  const float* v = (const float*)d_in[5];
  float* out = (float*)d_out;
  char* ws = (char*)d_ws;
  unsigned short* w1b = (unsigned short*)ws;            /* 2 MB */
  float* u = (float*)(ws + 2097152);                    /* 128 KB */
  float* spart = (float*)(ws + 2097152 + 131072);       /* 1 MB */
  unsigned short* enc16 =
      (unsigned short*)(ws + 2097152 + 131072 + 1048576); /* 128 MB */
  const size_t NEED = 2097152ull + 131072ull + 1048576ull + 134217728ull;
  const int big = (ws_size >= NEED) ? 1 : 0;

  w1cvt_kernel<<<512, 256, 0, stream>>>(W1, w1b);
  dec_proj_kernel<<<1024, 256, 0, stream>>>(dec, W2, u);
  scores_kernel<<<2048, 256, 0, stream>>>(enc, w1b, u, v, spart, enc16, big);
  softmax_kernel<<<32, 256, 0, stream>>>(spart, out, mask);
  if (big) {
    context16_kernel<<<256, 256, 0, stream>>>(enc16, out);
  } else {
    context_kernel<<<256, 256, 0, stream>>>(enc, out);
  }
}

// Round 19
// 288.237 us; speedup vs baseline: 1.0846x; 1.0846x over previous
//
#include <hip/hip_runtime.h>
#include <stdint.h>

typedef __bf16 bf16x8 __attribute__((ext_vector_type(8)));
typedef float f32x4 __attribute__((ext_vector_type(4)));
typedef unsigned short ushort8v __attribute__((ext_vector_type(8)));

__device__ __forceinline__ void gload_lds16(const void* g, void* l) {
  __builtin_amdgcn_global_load_lds(
      (const __attribute__((address_space(1))) void*)g,
      (__attribute__((address_space(3))) void*)l, 16, 0, 0);
}

__device__ __forceinline__ unsigned short f2bf(float f) {
  union { float f; unsigned int u; } x; x.f = f;
  unsigned int r = x.u + 0x7FFFu + ((x.u >> 16) & 1u);
  return (unsigned short)(r >> 16);
}

__device__ __forceinline__ float ftanh(float x) {
  float ax = fabsf(x);
  float e = __expf(-2.0f * ax);
  float r = (1.0f - e) / (1.0f + e);
  return copysignf(r, x);
}

// native bf16 casts: compiler emits v_cvt_pk_bf16_f32 (1 op / 2 elems)
__device__ __forceinline__ bf16x8 cvt8(float4 a, float4 b) {
  bf16x8 o;
  o[0] = (__bf16)a.x; o[1] = (__bf16)a.y; o[2] = (__bf16)a.z; o[3] = (__bf16)a.w;
  o[4] = (__bf16)b.x; o[5] = (__bf16)b.y; o[6] = (__bf16)b.z; o[7] = (__bf16)b.w;
  return o;
}

// -------- W1 f32 -> bf16, 16 KB chunks, slot-swizzled (R13-proven) ------
__global__ __launch_bounds__(256) void w1cvt_kernel(
    const float* __restrict__ W1, unsigned short* __restrict__ w1b) {
  const int g = blockIdx.x * 256 + threadIdx.x;
  const int chunk = g >> 10;
  const int d16 = g & 1023;
  const int col = d16 >> 2, s = d16 & 3;
  const int np = chunk >> 5, ks = chunk & 31;
  const float* src = W1 + (size_t)(np * 256 + col) * 1024 + ks * 32 +
                     ((s ^ ((col >> 1) & 3)) * 8);
  const float4 v0 = *(const float4*)src;
  const float4 v1 = *(const float4*)(src + 4);
  ushort8v o;
  o[0] = f2bf(v0.x); o[1] = f2bf(v0.y); o[2] = f2bf(v0.z); o[3] = f2bf(v0.w);
  o[4] = f2bf(v1.x); o[5] = f2bf(v1.y); o[6] = f2bf(v1.z); o[7] = f2bf(v1.w);
  *((ushort8v*)w1b + g) = o;
}

// ---------------- u[b][a] = sum_d dec[b][d] * W2[a][d] ----------------
__global__ __launch_bounds__(256) void dec_proj_kernel(
    const float* __restrict__ dec, const float* __restrict__ W2,
    float* __restrict__ u) {
  __shared__ __align__(16) float w2s[1024];
  const int a = blockIdx.x;
  const int t = threadIdx.x;
  *(float4*)(w2s + t * 4) = *(const float4*)(W2 + (size_t)a * 1024 + t * 4);
  __syncthreads();
  const int wid = t >> 6, l = t & 63;
  for (int bi = 0; bi < 8; ++bi) {
    const int b = wid * 8 + bi;
    const float* dp = dec + (size_t)b * 1024;
    float acc = 0.f;
#pragma unroll
    for (int i = 0; i < 4; ++i) {
      const int k = i * 256 + l * 4;
      const float4 dv = *(const float4*)(dp + k);
      const float4 wv = *(const float4*)(w2s + k);
      acc = fmaf(dv.x, wv.x, acc); acc = fmaf(dv.y, wv.y, acc);
      acc = fmaf(dv.z, wv.z, acc); acc = fmaf(dv.w, wv.w, acc);
    }
#pragma unroll
    for (int m = 1; m < 64; m <<= 1) acc += __shfl_xor(acc, m, 64);
    if (l == 0) u[(size_t)b * 1024 + a] = acc;
  }
}

// ------- fused partial scores (R13 shape, native-cast staging) ---------
// 256 thr (2x2 waves), BM=128 BN=256 BK=32, acc[4][8] = 32 indep MFMA.
// A: native-cast staged (two pieces/thread, issue-early/write-late);
// B: gload_lds from pre-swizzled w1b. LDS 49 KB -> 2 blocks/CU.
__global__ __launch_bounds__(256, 2) void scores_kernel(
    const float* __restrict__ enc, const unsigned short* __restrict__ w1b,
    const float* __restrict__ u, const float* __restrict__ vvec,
    float* __restrict__ spart) {
  __shared__ __align__(16) char Al[16384];
  __shared__ __align__(16) char Bl[32768];
  __shared__ __align__(16) float sred[256];

  const int t = threadIdx.x;
  const int bid = blockIdx.x;
  const int np = (bid >> 3) & 3;
  const int panel = (bid & 7) | ((bid >> 5) << 3);
  const int m0 = panel * 128;
  const int n0 = np * 256;
  const int b = panel >> 4;
  const int l = t & 63, wid = t >> 6;
  const int wr = wid >> 1, wc = wid & 1;
  const int lm = l & 15, lg = l >> 4;

  const int soff = (lg ^ ((lm >> 1) & 3)) * 16;
  const int abase = (wr * 64 + lm) * 64 + soff;
  const int bbase = (wc * 128 + lm) * 64 + soff;
  const char* w1base = (const char*)w1b + (size_t)(np * 32) * 16384;
  const float* ub = u + (size_t)b * 1024;

  // A staging: thread t handles row0 = t>>2 and row0+64, k-slot s0 = t&3
  const int row0 = t >> 2;
  const int s0 = t & 3;
  const int xo = (s0 ^ ((row0 >> 1) & 3)) * 8;
  const float* srcA = enc + (size_t)(m0 + row0) * 1024 + xo;
  const int adst = t * 16;

  f32x4 acc[4][8];
#pragma unroll
  for (int mi = 0; mi < 4; ++mi)
#pragma unroll
    for (int ni = 0; ni < 8; ++ni) acc[mi][ni] = (f32x4){0.f, 0.f, 0.f, 0.f};

  // ---------- prologue: stage K-step 0 into buf 0 ----------
#pragma unroll
  for (int i = 0; i < 4; ++i)
    gload_lds16(w1base + i * 4096 + t * 16, Bl + i * 4096 + t * 16);
  {
    const float4 p0 = *(const float4*)srcA;
    const float4 p1 = *(const float4*)(srcA + 4);
    const float4 p2 = *(const float4*)(srcA + 65536);
    const float4 p3 = *(const float4*)(srcA + 65540);
    *(bf16x8*)(Al + adst) = cvt8(p0, p1);
    *(bf16x8*)(Al + 4096 + adst) = cvt8(p2, p3);
  }
  __syncthreads();

#pragma unroll 2
  for (int kt = 0; kt < 32; ++kt) {
    const int abuf = (kt & 1) * 8192;
    const int bbuf = (kt & 1) * 16384;
    float4 p0, p1, p2, p3;
    if (kt < 31) {
      const char* wn = w1base + (size_t)(kt + 1) * 16384;
#pragma unroll
      for (int i = 0; i < 4; ++i)
        gload_lds16(wn + i * 4096 + t * 16,
                    Bl + (bbuf ^ 16384) + i * 4096 + t * 16);
      const float* sa = srcA + (kt + 1) * 32;
      p0 = *(const float4*)sa;
      p1 = *(const float4*)(sa + 4);
      p2 = *(const float4*)(sa + 65536);
      p3 = *(const float4*)(sa + 65540);
    }
    bf16x8 af[4], bf[8];
#pragma unroll
    for (int mi = 0; mi < 4; ++mi)
      af[mi] = *(const bf16x8*)(Al + abuf + abase + mi * 1024);
#pragma unroll
    for (int ni = 0; ni < 8; ++ni)
      bf[ni] = *(const bf16x8*)(Bl + bbuf + bbase + ni * 1024);
    __builtin_amdgcn_s_setprio(1);
#pragma unroll
    for (int mi = 0; mi < 4; ++mi)
#pragma unroll
      for (int ni = 0; ni < 8; ++ni)
        acc[mi][ni] = __builtin_amdgcn_mfma_f32_16x16x32_bf16(
            af[mi], bf[ni], acc[mi][ni], 0, 0, 0);
    __builtin_amdgcn_s_setprio(0);
    if (kt < 31) {
      *(bf16x8*)(Al + (abuf ^ 8192) + adst) = cvt8(p0, p1);
      *(bf16x8*)(Al + (abuf ^ 8192) + 4096 + adst) = cvt8(p2, p3);
    }
    __syncthreads(); /* drains gloads + ds_writes; guards dbuf swap */
  }

  // epilogue: tanh + v-weighted column reduction (R13-proven)
  float rowp[4][4];
#pragma unroll
  for (int mi = 0; mi < 4; ++mi)
#pragma unroll
    for (int j = 0; j < 4; ++j) rowp[mi][j] = 0.f;
#pragma unroll
  for (int ni = 0; ni < 8; ++ni) {
    const int colA = n0 + wc * 128 + ni * 16 + lm;
    const float uu = ub[colA], vv = vvec[colA];
#pragma unroll
    for (int mi = 0; mi < 4; ++mi)
#pragma unroll
      for (int j = 0; j < 4; ++j)
        rowp[mi][j] += ftanh(acc[mi][ni][j] + uu) * vv;
  }
#pragma unroll
  for (int m = 1; m < 16; m <<= 1)
#pragma unroll
    for (int mi = 0; mi < 4; ++mi)
#pragma unroll
      for (int j = 0; j < 4; ++j) rowp[mi][j] += __shfl_xor(rowp[mi][j], m, 64);
  if (lm == 0) {
#pragma unroll
    for (int mi = 0; mi < 4; ++mi)
#pragma unroll
      for (int j = 0; j < 4; ++j)
        sred[wc * 128 + wr * 64 + mi * 16 + lg * 4 + j] = rowp[mi][j];
  }
  __syncthreads();
  if (t < 128) {
    spart[(size_t)np * 65536 + m0 + t] = sred[t] + sred[128 + t];
  }
}

// -------- masked softmax over L: sums 4 partials, writes attn ----------
__global__ __launch_bounds__(256) void softmax_kernel(
    const float* __restrict__ spart, float* __restrict__ out,
    const int* __restrict__ mask) {
  __shared__ float wred[4];
  const int bidx = blockIdx.x;
  const int t = threadIdx.x;
  const int r8 = bidx * 2048 + t * 8;
  float* at = out + 32768 + (size_t)bidx * 2048;
  const int* mk = mask + (size_t)bidx * 2048;
  float v[8] = {0.f, 0.f, 0.f, 0.f, 0.f, 0.f, 0.f, 0.f};
#pragma unroll
  for (int np = 0; np < 4; ++np) {
    const float4 s0 = *(const float4*)(spart + (size_t)np * 65536 + r8);
    const float4 s1 = *(const float4*)(spart + (size_t)np * 65536 + r8 + 4);
    v[0] += s0.x; v[1] += s0.y; v[2] += s0.z; v[3] += s0.w;
    v[4] += s1.x; v[5] += s1.y; v[6] += s1.z; v[7] += s1.w;
  }
  const int4 q0 = *(const int4*)(mk + t * 8);
  const int4 q1 = *(const int4*)(mk + t * 8 + 4);
  int q[8] = {q0.x, q0.y, q0.z, q0.w, q1.x, q1.y, q1.z, q1.w};
  float mx = -3.0e38f;
#pragma unroll
  for (int j = 0; j < 8; ++j) if (q[j] != 0) mx = fmaxf(mx, v[j]);
#pragma unroll
  for (int m = 1; m < 64; m <<= 1) mx = fmaxf(mx, __shfl_xor(mx, m, 64));
  if ((t & 63) == 0) wred[t >> 6] = mx;
  __syncthreads();
  mx = fmaxf(fmaxf(wred[0], wred[1]), fmaxf(wred[2], wred[3]));
  __syncthreads();
  float pp[8]; float sum = 0.f;
#pragma unroll
  for (int j = 0; j < 8; ++j) {
    pp[j] = (q[j] != 0) ? __expf(v[j] - mx) : 0.f;
    sum += pp[j];
  }
#pragma unroll
  for (int m = 1; m < 64; m <<= 1) sum += __shfl_xor(sum, m, 64);
  if ((t & 63) == 0) wred[t >> 6] = sum;
  __syncthreads();
  sum = (wred[0] + wred[1]) + (wred[2] + wred[3]);
  const float inv = 1.0f / sum;
  const float4 o0 = {pp[0] * inv, pp[1] * inv, pp[2] * inv, pp[3] * inv};
  const float4 o1 = {pp[4] * inv, pp[5] * inv, pp[6] * inv, pp[7] * inv};
  *(float4*)(at + t * 8) = o0;
  *(float4*)(at + t * 8 + 4) = o1;
}

// -------- context[b][e] = sum_l attn[b][l] * enc[b][l][e] (R13-proven) --
__global__ __launch_bounds__(256) void context_kernel(
    const float* __restrict__ enc, float* __restrict__ out) {
  __shared__ __align__(16) float attnS[2048];
  __shared__ __align__(16) float red[8 * 128];
  const int bid = blockIdx.x;
  const int b = bid >> 3, ec = bid & 7;
  const int e0 = ec * 128;
  const int t = threadIdx.x;
  const float* attn = out + 32768 + (size_t)b * 2048;
#pragma unroll
  for (int i = 0; i < 8; ++i) attnS[i * 256 + t] = attn[i * 256 + t];
  __syncthreads();
  const int el = (t & 31) * 4;
  const int ls = t >> 5;
  f32x4 acc = {0.f, 0.f, 0.f, 0.f};
  const float* ebase = enc + (size_t)b * 2048 * 1024 + e0 + el;
  for (int l2 = ls; l2 < 2048; l2 += 8) {
    const float a = attnS[l2];
    const float4 ev = *(const float4*)(ebase + (size_t)l2 * 1024);
    acc[0] = fmaf(a, ev.x, acc[0]);
    acc[1] = fmaf(a, ev.y, acc[1]);
    acc[2] = fmaf(a, ev.z, acc[2]);
    acc[3] = fmaf(a, ev.w, acc[3]);
  }
  *(f32x4*)(red + ls * 128 + el) = acc;
  __syncthreads();
  if (t < 128) {
    float s = 0.f;
#pragma unroll
    for (int i = 0; i < 8; ++i) s += red[i * 128 + t];
    out[(size_t)b * 1024 + e0 + t] = s;
  }
}

extern "C" void kernel_launch(void* const* d_in, const int* in_sizes, int n_in,
                              void* d_out, int out_size, void* d_ws,
                              size_t ws_size, hipStream_t stream) {
  const float* enc = (const float*)d_in[0];
  const float* dec = (const float*)d_in[1];
  const int* mask = (const int*)d_in[2];
  const float* W1 = (const float*)d_in[3];
  const float* W2 = (const float*)d_in[4];
  const float* v = (const float*)d_in[5];
  float* out = (float*)d_out;
  char* ws = (char*)d_ws;
  unsigned short* w1b = (unsigned short*)ws;      /* 2 MB pre-swizzled W1 */
  float* u = (float*)(ws + 2097152);              /* 128 KB dec proj */
  float* spart = (float*)(ws + 2097152 + 131072); /* 1 MB partials */

  w1cvt_kernel<<<512, 256, 0, stream>>>(W1, w1b);
  dec_proj_kernel<<<1024, 256, 0, stream>>>(dec, W2, u);
  scores_kernel<<<2048, 256, 0, stream>>>(enc, w1b, u, v, spart);
  softmax_kernel<<<32, 256, 0, stream>>>(spart, out, mask);
  context_kernel<<<256, 256, 0, stream>>>(enc, out);
}

// Round 20
// 271.378 us; speedup vs baseline: 1.1519x; 1.0621x over previous
//
#include <hip/hip_runtime.h>
#include <stdint.h>

typedef __bf16 bf16x8 __attribute__((ext_vector_type(8)));
typedef float f32x4 __attribute__((ext_vector_type(4)));
typedef unsigned short ushort8v __attribute__((ext_vector_type(8)));

__device__ __forceinline__ void gload_lds16(const void* g, void* l) {
  __builtin_amdgcn_global_load_lds(
      (const __attribute__((address_space(1))) void*)g,
      (__attribute__((address_space(3))) void*)l, 16, 0, 0);
}

__device__ __forceinline__ unsigned short f2bf(float f) {
  union { float f; unsigned int u; } x; x.f = f;
  unsigned int r = x.u + 0x7FFFu + ((x.u >> 16) & 1u);
  return (unsigned short)(r >> 16);
}

__device__ __forceinline__ float ftanh(float x) {
  float ax = fabsf(x);
  float e = __expf(-2.0f * ax);
  float r = (1.0f - e) / (1.0f + e);
  return copysignf(r, x);
}

// -------- W1 f32 -> bf16, 32 KB chunks for BN=512 x BK=32 tiles --------
// chunk c = np*32 + kt covers cols [np*512,+512), k [kt*32,+32).
// Piece (col, s) at byte col*64 + s*16 holds k-slot s^((col>>1)&3)
// (R13-proven swizzle family: 2-way banks max, measured 0 conflicts).
__global__ __launch_bounds__(256) void w1cvt_kernel(
    const float* __restrict__ W1, unsigned short* __restrict__ w1b) {
  const int g = blockIdx.x * 256 + threadIdx.x; /* 16-B piece id */
  const int chunk = g >> 11;                    /* 32 KB = 2048 pieces */
  const int d = g & 2047;
  const int col = d >> 2, s = d & 3;
  const int np = chunk >> 5, kt = chunk & 31;
  const float* src = W1 + (size_t)(np * 512 + col) * 1024 + kt * 32 +
                     ((s ^ ((col >> 1) & 3)) * 8);
  const float4 v0 = *(const float4*)src;
  const float4 v1 = *(const float4*)(src + 4);
  ushort8v o;
  o[0] = f2bf(v0.x); o[1] = f2bf(v0.y); o[2] = f2bf(v0.z); o[3] = f2bf(v0.w);
  o[4] = f2bf(v1.x); o[5] = f2bf(v1.y); o[6] = f2bf(v1.z); o[7] = f2bf(v1.w);
  *((ushort8v*)w1b + g) = o;
}

// ---------------- u[b][a] = sum_d dec[b][d] * W2[a][d] ----------------
__global__ __launch_bounds__(256) void dec_proj_kernel(
    const float* __restrict__ dec, const float* __restrict__ W2,
    float* __restrict__ u) {
  __shared__ __align__(16) float w2s[1024];
  const int a = blockIdx.x;
  const int t = threadIdx.x;
  *(float4*)(w2s + t * 4) = *(const float4*)(W2 + (size_t)a * 1024 + t * 4);
  __syncthreads();
  const int wid = t >> 6, l = t & 63;
  for (int bi = 0; bi < 8; ++bi) {
    const int b = wid * 8 + bi;
    const float* dp = dec + (size_t)b * 1024;
    float acc = 0.f;
#pragma unroll
    for (int i = 0; i < 4; ++i) {
      const int k = i * 256 + l * 4;
      const float4 dv = *(const float4*)(dp + k);
      const float4 wv = *(const float4*)(w2s + k);
      acc = fmaf(dv.x, wv.x, acc); acc = fmaf(dv.y, wv.y, acc);
      acc = fmaf(dv.z, wv.z, acc); acc = fmaf(dv.w, wv.w, acc);
    }
#pragma unroll
    for (int m = 1; m < 64; m <<= 1) acc += __shfl_xor(acc, m, 64);
    if (l == 0) u[(size_t)b * 1024 + a] = acc;
  }
}

// ------- fused partial scores: BM=128 x BN=512, no prepass -------------
// 512 thr (2 wr x 4 wc waves), per wave 64x128 out: acc[4][8] = 32
// INDEPENDENT MFMAs per K-step (R14-proven slot shape). A: VALU-staged
// f32->bf16 in-kernel (2x total redundancy, issue-early/write-late);
// B: global_load_lds from pre-swizzled w1b. LDS 16K A-dbuf + 64K B-dbuf
// = 80 KB -> 2 blocks/CU. np-pair of a panel lands on the same XCD
// (bid = same mod 8) -> A-panel's 2nd read is L2-resident.
__global__ __launch_bounds__(512, 2) void scores_kernel(
    const float* __restrict__ enc, const unsigned short* __restrict__ w1b,
    const float* __restrict__ u, const float* __restrict__ vvec,
    float* __restrict__ spart) {
  __shared__ __align__(16) char Al[16384];
  __shared__ __align__(16) char Bl[65536];

  const int t = threadIdx.x;
  const int bid = blockIdx.x;
  const int np = (bid >> 3) & 1;                   /* 0..1 */
  const int panel = (bid & 7) | ((bid >> 4) << 3); /* 0..511 */
  const int m0 = panel * 128;
  const int b = panel >> 4; /* 16 panels per batch */
  const int l = t & 63, wid = t >> 6;
  const int wr = wid >> 2, wc = wid & 3;
  const int lm = l & 15, lg = l >> 4;

  const int soff = (lg ^ ((lm >> 1) & 3)) * 16;
  const int abase = (wr * 64 + lm) * 64 + soff;  /* + mi*1024 */
  const int bbase = (wc * 128 + lm) * 64 + soff; /* + ni*1024 */
  const char* w1base = (const char*)w1b + (size_t)np * 1048576;
  const float* ub = u + (size_t)b * 1024;

  // A staging (R13-proven): thread t handles row0 = t>>2, k-slot s0 = t&3
  const int row0 = t >> 2;
  const int s0 = t & 3;
  const int xo = (s0 ^ ((row0 >> 1) & 3)) * 8;
  const float* srcA = enc + (size_t)(m0 + row0) * 1024 + xo;
  const int adst = t * 16;

  f32x4 acc[4][8];
#pragma unroll
  for (int mi = 0; mi < 4; ++mi)
#pragma unroll
    for (int ni = 0; ni < 8; ++ni) acc[mi][ni] = (f32x4){0.f, 0.f, 0.f, 0.f};

  // ---------- prologue: stage K-step 0 into buf 0 ----------
#pragma unroll
  for (int i = 0; i < 4; ++i)
    gload_lds16(w1base + (i * 512 + t) * 16, Bl + (i * 512 + t) * 16);
  {
    const float4 p0 = *(const float4*)srcA;
    const float4 p1 = *(const float4*)(srcA + 4);
    ushort8v o;
    o[0] = f2bf(p0.x); o[1] = f2bf(p0.y); o[2] = f2bf(p0.z); o[3] = f2bf(p0.w);
    o[4] = f2bf(p1.x); o[5] = f2bf(p1.y); o[6] = f2bf(p1.z); o[7] = f2bf(p1.w);
    *(ushort8v*)(Al + adst) = o;
  }
  __syncthreads();

#pragma unroll 2
  for (int kt = 0; kt < 32; ++kt) {
    const int abuf = (kt & 1) * 8192;
    const int bbuf = (kt & 1) * 32768;
    float4 p0, p1;
    if (kt < 31) {
      const char* wn = w1base + (size_t)(kt + 1) * 32768;
#pragma unroll
      for (int i = 0; i < 4; ++i)
        gload_lds16(wn + (i * 512 + t) * 16,
                    Bl + (bbuf ^ 32768) + (i * 512 + t) * 16);
      const float* sa = srcA + (kt + 1) * 32;
      p0 = *(const float4*)sa;
      p1 = *(const float4*)(sa + 4);
    }
    bf16x8 af[4], bf[8];
#pragma unroll
    for (int mi = 0; mi < 4; ++mi)
      af[mi] = *(const bf16x8*)(Al + abuf + abase + mi * 1024);
#pragma unroll
    for (int ni = 0; ni < 8; ++ni)
      bf[ni] = *(const bf16x8*)(Bl + bbuf + bbase + ni * 1024);
    __builtin_amdgcn_s_setprio(1);
#pragma unroll
    for (int mi = 0; mi < 4; ++mi)
#pragma unroll
      for (int ni = 0; ni < 8; ++ni)
        acc[mi][ni] = __builtin_amdgcn_mfma_f32_16x16x32_bf16(
            af[mi], bf[ni], acc[mi][ni], 0, 0, 0);
    __builtin_amdgcn_s_setprio(0);
    if (kt < 31) {
      ushort8v o;
      o[0] = f2bf(p0.x); o[1] = f2bf(p0.y); o[2] = f2bf(p0.z); o[3] = f2bf(p0.w);
      o[4] = f2bf(p1.x); o[5] = f2bf(p1.y); o[6] = f2bf(p1.z); o[7] = f2bf(p1.w);
      *(ushort8v*)(Al + (abuf ^ 8192) + adst) = o;
    }
    __syncthreads(); /* drains gloads + ds_writes; guards dbuf swap */
  }

  // epilogue: tanh + v-weighted column reduction (R13-proven form)
  float rowp[4][4];
#pragma unroll
  for (int mi = 0; mi < 4; ++mi)
#pragma unroll
    for (int j = 0; j < 4; ++j) rowp[mi][j] = 0.f;
#pragma unroll
  for (int ni = 0; ni < 8; ++ni) {
    const int colA = np * 512 + wc * 128 + ni * 16 + lm;
    const float uu = ub[colA], vv = vvec[colA];
#pragma unroll
    for (int mi = 0; mi < 4; ++mi)
#pragma unroll
      for (int j = 0; j < 4; ++j)
        rowp[mi][j] += ftanh(acc[mi][ni][j] + uu) * vv;
  }
#pragma unroll
  for (int m = 1; m < 16; m <<= 1)
#pragma unroll
    for (int mi = 0; mi < 4; ++mi)
#pragma unroll
      for (int j = 0; j < 4; ++j) rowp[mi][j] += __shfl_xor(rowp[mi][j], m, 64);
  float* sred = (float*)Al; /* overlay; Al dead after final barrier */
  if (lm == 0) {
#pragma unroll
    for (int mi = 0; mi < 4; ++mi)
#pragma unroll
      for (int j = 0; j < 4; ++j)
        sred[wc * 128 + wr * 64 + mi * 16 + lg * 4 + j] = rowp[mi][j];
  }
  __syncthreads();
  if (t < 128) {
    spart[(size_t)np * 65536 + m0 + t] =
        sred[t] + sred[128 + t] + sred[256 + t] + sred[384 + t];
  }
}

// -------- masked softmax over L: sums 2 partials, writes attn ----------
__global__ __launch_bounds__(256) void softmax_kernel(
    const float* __restrict__ spart, float* __restrict__ out,
    const int* __restrict__ mask) {
  __shared__ float wred[4];
  const int bidx = blockIdx.x;
  const int t = threadIdx.x;
  const int r8 = bidx * 2048 + t * 8;
  float* at = out + 32768 + (size_t)bidx * 2048;
  const int* mk = mask + (size_t)bidx * 2048;
  float v[8];
  {
    const float4 s0 = *(const float4*)(spart + r8);
    const float4 s1 = *(const float4*)(spart + r8 + 4);
    const float4 s2 = *(const float4*)(spart + 65536 + r8);
    const float4 s3 = *(const float4*)(spart + 65536 + r8 + 4);
    v[0] = s0.x + s2.x; v[1] = s0.y + s2.y; v[2] = s0.z + s2.z;
    v[3] = s0.w + s2.w; v[4] = s1.x + s3.x; v[5] = s1.y + s3.y;
    v[6] = s1.z + s3.z; v[7] = s1.w + s3.w;
  }
  const int4 q0 = *(const int4*)(mk + t * 8);
  const int4 q1 = *(const int4*)(mk + t * 8 + 4);
  int q[8] = {q0.x, q0.y, q0.z, q0.w, q1.x, q1.y, q1.z, q1.w};
  float mx = -3.0e38f;
#pragma unroll
  for (int j = 0; j < 8; ++j) if (q[j] != 0) mx = fmaxf(mx, v[j]);
#pragma unroll
  for (int m = 1; m < 64; m <<= 1) mx = fmaxf(mx, __shfl_xor(mx, m, 64));
  if ((t & 63) == 0) wred[t >> 6] = mx;
  __syncthreads();
  mx = fmaxf(fmaxf(wred[0], wred[1]), fmaxf(wred[2], wred[3]));
  __syncthreads();
  float pp[8]; float sum = 0.f;
#pragma unroll
  for (int j = 0; j < 8; ++j) {
    pp[j] = (q[j] != 0) ? __expf(v[j] - mx) : 0.f;
    sum += pp[j];
  }
#pragma unroll
  for (int m = 1; m < 64; m <<= 1) sum += __shfl_xor(sum, m, 64);
  if ((t & 63) == 0) wred[t >> 6] = sum;
  __syncthreads();
  sum = (wred[0] + wred[1]) + (wred[2] + wred[3]);
  const float inv = 1.0f / sum;
  const float4 o0 = {pp[0] * inv, pp[1] * inv, pp[2] * inv, pp[3] * inv};
  const float4 o1 = {pp[4] * inv, pp[5] * inv, pp[6] * inv, pp[7] * inv};
  *(float4*)(at + t * 8) = o0;
  *(float4*)(at + t * 8 + 4) = o1;
}

// -------- context[b][e] = sum_l attn[b][l] * enc[b][l][e] (R13-proven) --
__global__ __launch_bounds__(256) void context_kernel(
    const float* __restrict__ enc, float* __restrict__ out) {
  __shared__ __align__(16) float attnS[2048];
  __shared__ __align__(16) float red[8 * 128];
  const int bid = blockIdx.x;
  const int b = bid >> 3, ec = bid & 7;
  const int e0 = ec * 128;
  const int t = threadIdx.x;
  const float* attn = out + 32768 + (size_t)b * 2048;
#pragma unroll
  for (int i = 0; i < 8; ++i) attnS[i * 256 + t] = attn[i * 256 + t];
  __syncthreads();
  const int el = (t & 31) * 4;
  const int ls = t >> 5;
  f32x4 acc = {0.f, 0.f, 0.f, 0.f};
  const float* ebase = enc + (size_t)b * 2048 * 1024 + e0 + el;
  for (int l2 = ls; l2 < 2048; l2 += 8) {
    const float a = attnS[l2];
    const float4 ev = *(const float4*)(ebase + (size_t)l2 * 1024);
    acc[0] = fmaf(a, ev.x, acc[0]);
    acc[1] = fmaf(a, ev.y, acc[1]);
    acc[2] = fmaf(a, ev.z, acc[2]);
    acc[3] = fmaf(a, ev.w, acc[3]);
  }
  *(f32x4*)(red + ls * 128 + el) = acc;
  __syncthreads();
  if (t < 128) {
    float s = 0.f;
#pragma unroll
    for (int i = 0; i < 8; ++i) s += red[i * 128 + t];
    out[(size_t)b * 1024 + e0 + t] = s;
  }
}

extern "C" void kernel_launch(void* const* d_in, const int* in_sizes, int n_in,
                              void* d_out, int out_size, void* d_ws,
                              size_t ws_size, hipStream_t stream) {
  const float* enc = (const float*)d_in[0];
  const float* dec = (const float*)d_in[1];
  const int* mask = (const int*)d_in[2];
  const float* W1 = (const float*)d_in[3];
  const float* W2 = (const float*)d_in[4];
  const float* v = (const float*)d_in[5];
  float* out = (float*)d_out;
  char* ws = (char*)d_ws;
  unsigned short* w1b = (unsigned short*)ws;      /* 2 MB pre-swizzled W1 */
  float* u = (float*)(ws + 2097152);              /* 128 KB dec proj */
  float* spart = (float*)(ws + 2097152 + 131072); /* 512 KB partials */

  w1cvt_kernel<<<512, 256, 0, stream>>>(W1, w1b);
  dec_proj_kernel<<<1024, 256, 0, stream>>>(dec, W2, u);
  scores_kernel<<<1024, 512, 0, stream>>>(enc, w1b, u, v, spart);
  softmax_kernel<<<32, 256, 0, stream>>>(spart, out, mask);
  context_kernel<<<256, 256, 0, stream>>>(enc, out);
}